// Round 1
// baseline (398.789 us; speedup 1.0000x reference)
//
#include <hip/hip_runtime.h>
#include <math.h>

#define NB  16
#define NN  307
#define KCH 3
#define IND 66      // INPUT_DIM + HIDDEN
#define KI  198     // KCH * IND
#define HID 64
#define HG  128     // 2 * HIDDEN

// K0: combined = concat(xt, h) -> (B*N, 66)
__global__ void build_combined(const float* __restrict__ xt,
                               const float* __restrict__ h,
                               float* __restrict__ xc) {
    int idx = blockIdx.x * blockDim.x + threadIdx.x;
    const int total = NB * NN * IND;
    if (idx >= total) return;
    int i  = idx % IND;
    int bn = idx / IND;
    xc[idx] = (i < 2) ? xt[bn * 2 + i] : h[bn * HID + (i - 2)];
}

// sup[b,n,k*IND+i] = sum_m G[k,n,m] * x[b,m,i]   (x is (B*N,66) packed)
__global__ void gcn_kernel(const float* __restrict__ G,
                           const float* __restrict__ x,
                           float* __restrict__ sup) {
    int idx = blockIdx.x * blockDim.x + threadIdx.x;
    const int total = NB * NN * KI;
    if (idx >= total) return;
    int ki = idx % KI;
    int bn = idx / KI;
    int n  = bn % NN;
    int b  = bn / NN;
    int k  = ki / IND;
    int i  = ki % IND;
    const float* gp = G + (size_t)(k * NN + n) * NN;
    const float* xp = x + (size_t)b * NN * IND + i;
    float acc = 0.f;
    #pragma unroll 4
    for (int m = 0; m < NN; ++m)
        acc += gp[m] * xp[(size_t)m * IND];
    sup[idx] = acc;
}

// K2: gates = sigmoid(sup . W + b); z stored; cand = concat(xt, r*h)
__global__ void gate_kernel(const float* __restrict__ sup,
                            const float* __restrict__ W,
                            const float* __restrict__ bias,
                            const float* __restrict__ xt,
                            const float* __restrict__ h,
                            float* __restrict__ z_out,
                            float* __restrict__ cand) {
    __shared__ float s[KI];
    const int bn  = blockIdx.x;
    const int tid = threadIdx.x;   // 0..127 -> gate column
    for (int t = tid; t < KI; t += 128) s[t] = sup[bn * KI + t];
    __syncthreads();
    float acc = bias[bn * HG + tid];
    const float* Wp = W + (size_t)bn * KI * HG + tid;
    #pragma unroll 2
    for (int i = 0; i < KI; ++i)
        acc += s[i] * Wp[(size_t)i * HG];
    float g = 1.0f / (1.0f + expf(-acc));
    if (tid < HID) {
        z_out[bn * HID + tid] = g;              // z
    } else {
        int hh = tid - HID;                     // r
        cand[bn * IND + 2 + hh] = g * h[bn * HID + hh];
    }
    if (tid < 2) cand[bn * IND + tid] = xt[bn * 2 + tid];
}

// K4: n = tanh(sup2 . Wu + bu); out = z*n + (1-z)*h   (2 nodes per block)
__global__ void update_kernel(const float* __restrict__ sup,
                              const float* __restrict__ W,
                              const float* __restrict__ bias,
                              const float* __restrict__ z,
                              const float* __restrict__ h,
                              float* __restrict__ out) {
    __shared__ float s[2 * KI];
    const int tid = threadIdx.x;
    const int bn0 = blockIdx.x * 2;
    for (int t = tid; t < 2 * KI; t += 128) s[t] = sup[bn0 * KI + t];
    __syncthreads();
    const int node = tid / HID;   // 0 or 1
    const int hh   = tid % HID;
    const int bn   = bn0 + node;
    float acc = bias[bn * HID + hh];
    const float* Wp = W + (size_t)bn * KI * HID + hh;
    const float* sp = s + node * KI;
    #pragma unroll 2
    for (int i = 0; i < KI; ++i)
        acc += sp[i] * Wp[(size_t)i * HID];
    float nn = tanhf(acc);
    float zz = z[bn * HID + hh];
    float hv = h[bn * HID + hh];
    out[bn * HID + hh] = zz * nn + (1.f - zz) * hv;
}

extern "C" void kernel_launch(void* const* d_in, const int* in_sizes, int n_in,
                              void* d_out, int out_size, void* d_ws, size_t ws_size,
                              hipStream_t stream) {
    const float* G  = (const float*)d_in[0];
    const float* xt = (const float*)d_in[1];
    const float* h  = (const float*)d_in[2];
    const float* Wg = (const float*)d_in[3];
    const float* bg = (const float*)d_in[4];
    const float* Wu = (const float*)d_in[5];
    const float* bu = (const float*)d_in[6];
    float* out = (float*)d_out;

    float* ws      = (float*)d_ws;
    float* buf_x   = ws;                          // NB*NN*IND  (combined, then cand)
    float* buf_sup = buf_x + NB * NN * IND;       // NB*NN*KI
    float* buf_z   = buf_sup + NB * NN * KI;      // NB*NN*HID

    const int totC = NB * NN * IND;
    build_combined<<<(totC + 255) / 256, 256, 0, stream>>>(xt, h, buf_x);

    const int totS = NB * NN * KI;
    gcn_kernel<<<(totS + 255) / 256, 256, 0, stream>>>(G, buf_x, buf_sup);

    gate_kernel<<<NB * NN, 128, 0, stream>>>(buf_sup, Wg, bg, xt, h, buf_z, buf_x);

    gcn_kernel<<<(totS + 255) / 256, 256, 0, stream>>>(G, buf_x, buf_sup);

    update_kernel<<<NB * NN / 2, 128, 0, stream>>>(buf_sup, Wu, bu, buf_z, h, out);
}

// Round 2
// 277.353 us; speedup vs baseline: 1.4378x; 1.4378x over previous
//
#include <hip/hip_runtime.h>
#include <math.h>

#define NB  16
#define NN  307
#define KCH 3
#define IND 66      // INPUT_DIM + HIDDEN
#define KI  198     // KCH * IND
#define HID 64
#define HG  128     // 2 * HIDDEN

// K0: combined = concat(xt, h) -> (B*N, 66)
__global__ void build_combined(const float* __restrict__ xt,
                               const float* __restrict__ h,
                               float* __restrict__ xc) {
    int idx = blockIdx.x * blockDim.x + threadIdx.x;
    const int total = NB * NN * IND;
    if (idx >= total) return;
    int i  = idx % IND;
    int bn = idx / IND;
    xc[idx] = (i < 2) ? xt[bn * 2 + i] : h[bn * HID + (i - 2)];
}

// sup[b,n,k*IND+i] = sum_m G[k,n,m] * x[b,m,i]; one thread per (b,n,i),
// computes all 3 k values -> x column read once, reused 3x.
__global__ void gcn_kernel(const float* __restrict__ G,
                           const float* __restrict__ x,
                           float* __restrict__ sup) {
    int idx = blockIdx.x * blockDim.x + threadIdx.x;
    const int total = NB * NN * IND;
    if (idx >= total) return;
    int i  = idx % IND;
    int bn = idx / IND;
    int n  = bn % NN;
    int b  = bn / NN;
    const float* g0 = G + (size_t)(0 * NN + n) * NN;
    const float* g1 = G + (size_t)(1 * NN + n) * NN;
    const float* g2 = G + (size_t)(2 * NN + n) * NN;
    const float* xp = x + (size_t)b * NN * IND + i;
    float a0 = 0.f, a1 = 0.f, a2 = 0.f;
    #pragma unroll 4
    for (int m = 0; m < NN; ++m) {
        float xm = xp[(size_t)m * IND];
        a0 += g0[m] * xm;
        a1 += g1[m] * xm;
        a2 += g2[m] * xm;
    }
    float* sp = sup + (size_t)bn * KI + i;
    sp[0]        = a0;
    sp[IND]      = a1;
    sp[2 * IND]  = a2;
}

// K2: gates = sigmoid(sup . W + b); z stored; cand = concat(xt, r*h)
// 128 threads: r = tid>>5 (row group 0..3), c4 = (tid&31)*4 (col quad).
// float4 W loads, LDS reduction across the 4 row groups.
__global__ void gate_kernel(const float* __restrict__ sup,
                            const float* __restrict__ W,
                            const float* __restrict__ bias,
                            const float* __restrict__ xt,
                            const float* __restrict__ h,
                            float* __restrict__ z_out,
                            float* __restrict__ cand) {
    __shared__ float s[KI];
    __shared__ float red[4][HG];
    const int bn  = blockIdx.x;
    const int tid = threadIdx.x;
    for (int t = tid; t < KI; t += 128) s[t] = sup[bn * KI + t];
    __syncthreads();
    const int r  = tid >> 5;
    const int c4 = (tid & 31) * 4;
    const float* Wp = W + (size_t)bn * KI * HG + c4;
    float4 acc = make_float4(0.f, 0.f, 0.f, 0.f);
    #pragma unroll 4
    for (int i = r; i < KI; i += 4) {
        float4 w = *(const float4*)(Wp + (size_t)i * HG);
        float sv = s[i];
        acc.x += sv * w.x; acc.y += sv * w.y;
        acc.z += sv * w.z; acc.w += sv * w.w;
    }
    red[r][c4 + 0] = acc.x; red[r][c4 + 1] = acc.y;
    red[r][c4 + 2] = acc.z; red[r][c4 + 3] = acc.w;
    __syncthreads();
    const int col = tid;  // 0..127
    float a = bias[bn * HG + col] + red[0][col] + red[1][col] + red[2][col] + red[3][col];
    float g = 1.0f / (1.0f + expf(-a));
    if (col < HID) {
        z_out[bn * HID + col] = g;                 // z
    } else {
        int hh = col - HID;                        // r gate
        cand[bn * IND + 2 + hh] = g * h[bn * HID + hh];
    }
    if (col < 2) cand[bn * IND + col] = xt[bn * 2 + col];
}

// K4: n = tanh(sup2 . Wu + bu); out = z*n + (1-z)*h
// 128 threads: r = tid>>4 (0..7), c4 = (tid&15)*4. float4 W loads.
__global__ void update_kernel(const float* __restrict__ sup,
                              const float* __restrict__ W,
                              const float* __restrict__ bias,
                              const float* __restrict__ z,
                              const float* __restrict__ h,
                              float* __restrict__ out) {
    __shared__ float s[KI];
    __shared__ float red[8][HID];
    const int bn  = blockIdx.x;
    const int tid = threadIdx.x;
    for (int t = tid; t < KI; t += 128) s[t] = sup[bn * KI + t];
    __syncthreads();
    const int r  = tid >> 4;
    const int c4 = (tid & 15) * 4;
    const float* Wp = W + (size_t)bn * KI * HID + c4;
    float4 acc = make_float4(0.f, 0.f, 0.f, 0.f);
    #pragma unroll 4
    for (int i = r; i < KI; i += 8) {
        float4 w = *(const float4*)(Wp + (size_t)i * HID);
        float sv = s[i];
        acc.x += sv * w.x; acc.y += sv * w.y;
        acc.z += sv * w.z; acc.w += sv * w.w;
    }
    red[r][c4 + 0] = acc.x; red[r][c4 + 1] = acc.y;
    red[r][c4 + 2] = acc.z; red[r][c4 + 3] = acc.w;
    __syncthreads();
    if (tid < HID) {
        const int col = tid;
        float a = bias[bn * HID + col];
        #pragma unroll
        for (int rr = 0; rr < 8; ++rr) a += red[rr][col];
        float nn = tanhf(a);
        float zz = z[bn * HID + col];
        float hv = h[bn * HID + col];
        out[bn * HID + col] = zz * nn + (1.f - zz) * hv;
    }
}

extern "C" void kernel_launch(void* const* d_in, const int* in_sizes, int n_in,
                              void* d_out, int out_size, void* d_ws, size_t ws_size,
                              hipStream_t stream) {
    const float* G  = (const float*)d_in[0];
    const float* xt = (const float*)d_in[1];
    const float* h  = (const float*)d_in[2];
    const float* Wg = (const float*)d_in[3];
    const float* bg = (const float*)d_in[4];
    const float* Wu = (const float*)d_in[5];
    const float* bu = (const float*)d_in[6];
    float* out = (float*)d_out;

    float* ws      = (float*)d_ws;
    float* buf_x   = ws;                          // NB*NN*IND  (combined, then cand)
    float* buf_sup = buf_x + NB * NN * IND;       // NB*NN*KI
    float* buf_z   = buf_sup + NB * NN * KI;      // NB*NN*HID

    const int totC = NB * NN * IND;
    build_combined<<<(totC + 255) / 256, 256, 0, stream>>>(xt, h, buf_x);

    gcn_kernel<<<(totC + 255) / 256, 256, 0, stream>>>(G, buf_x, buf_sup);

    gate_kernel<<<NB * NN, 128, 0, stream>>>(buf_sup, Wg, bg, xt, h, buf_z, buf_x);

    gcn_kernel<<<(totC + 255) / 256, 256, 0, stream>>>(G, buf_x, buf_sup);

    update_kernel<<<NB * NN, 128, 0, stream>>>(buf_sup, Wu, bu, buf_z, h, out);
}

// Round 3
// 276.015 us; speedup vs baseline: 1.4448x; 1.0048x over previous
//
#include <hip/hip_runtime.h>
#include <math.h>

#define NB  16
#define NN  307
#define NNP 308     // padded reduction dim (multiple of 4; row stride 1232 B, 16B-aligned)
#define KCH 3
#define IND 66      // INPUT_DIM + HIDDEN
#define KI  198     // KCH * IND
#define HID 64
#define HG  128     // 2 * HIDDEN

// ws layout (floats)
#define OFF_GP   0
#define SZ_GP    (KCH * NN * NNP)          // 283,668
#define OFF_XT   (OFF_GP + SZ_GP)
#define SZ_XT    (NB * IND * NNP)          // 325,248
#define OFF_SUP  (OFF_XT + SZ_XT)
#define SZ_SUP   (NB * NN * KI)            // 972,432
#define OFF_Z    (OFF_SUP + SZ_SUP)

// K0: build padded G copy + transposed combined input x_T[b][i][m]
__global__ void prep_kernel(const float* __restrict__ G,
                            const float* __restrict__ xt,
                            const float* __restrict__ h,
                            float* __restrict__ G_p,
                            float* __restrict__ x_T) {
    int idx = blockIdx.x * blockDim.x + threadIdx.x;
    const int totG = KCH * NN * NNP;
    const int totX = NB * IND * NNP;
    if (idx < totG) {
        int mp = idx % NNP;
        int kn = idx / NNP;
        G_p[idx] = (mp < NN) ? G[kn * NN + mp] : 0.f;
    } else if (idx < totG + totX) {
        int j  = idx - totG;
        int mp = j % NNP;
        int bi = j / NNP;
        int i  = bi % IND;
        int b  = bi / IND;
        float v = 0.f;
        if (mp < NN)
            v = (i < 2) ? xt[(b * NN + mp) * 2 + i]
                        : h[(b * NN + mp) * HID + (i - 2)];
        x_T[j] = v;
    }
}

// sup[b,n,k*IND+i] = sum_m G[k,n,m] * x[b,m,i]; thread per (b,n,i), all 3 k.
// x_T (b,i,m) and G_p rows are contiguous in m -> float4 reduction.
__global__ void gcn_kernel(const float* __restrict__ G_p,
                           const float* __restrict__ x_T,
                           float* __restrict__ sup) {
    int idx = blockIdx.x * blockDim.x + threadIdx.x;
    const int total = NB * NN * IND;
    if (idx >= total) return;
    int i  = idx % IND;
    int bn = idx / IND;
    int n  = bn % NN;
    int b  = bn / NN;
    const float4* xp = (const float4*)(x_T + (size_t)(b * IND + i) * NNP);
    const float4* g0 = (const float4*)(G_p + (size_t)(0 * NN + n) * NNP);
    const float4* g1 = (const float4*)(G_p + (size_t)(1 * NN + n) * NNP);
    const float4* g2 = (const float4*)(G_p + (size_t)(2 * NN + n) * NNP);
    float a0 = 0.f, a1 = 0.f, a2 = 0.f;
    #pragma unroll 4
    for (int mm = 0; mm < NNP / 4; ++mm) {
        float4 x4 = xp[mm];
        float4 q0 = g0[mm];
        float4 q1 = g1[mm];
        float4 q2 = g2[mm];
        a0 += x4.x * q0.x + x4.y * q0.y + x4.z * q0.z + x4.w * q0.w;
        a1 += x4.x * q1.x + x4.y * q1.y + x4.z * q1.z + x4.w * q1.w;
        a2 += x4.x * q2.x + x4.y * q2.y + x4.z * q2.z + x4.w * q2.w;
    }
    float* sp = sup + (size_t)bn * KI + i;
    sp[0]       = a0;
    sp[IND]     = a1;
    sp[2 * IND] = a2;
}

// K2: gates = sigmoid(sup . W + b); z stored; cand written into x_T rows 2..65
__global__ void gate_kernel(const float* __restrict__ sup,
                            const float* __restrict__ W,
                            const float* __restrict__ bias,
                            const float* __restrict__ h,
                            float* __restrict__ z_out,
                            float* __restrict__ x_T) {
    __shared__ float s[KI];
    __shared__ float red[4][HG];
    const int bn  = blockIdx.x;
    const int tid = threadIdx.x;
    for (int t = tid; t < KI; t += 128) s[t] = sup[bn * KI + t];
    __syncthreads();
    const int r  = tid >> 5;
    const int c4 = (tid & 31) * 4;
    const float* Wp = W + (size_t)bn * KI * HG + c4;
    float4 acc = make_float4(0.f, 0.f, 0.f, 0.f);
    #pragma unroll 8
    for (int i = r; i < KI; i += 4) {
        float4 w = *(const float4*)(Wp + (size_t)i * HG);
        float sv = s[i];
        acc.x += sv * w.x; acc.y += sv * w.y;
        acc.z += sv * w.z; acc.w += sv * w.w;
    }
    red[r][c4 + 0] = acc.x; red[r][c4 + 1] = acc.y;
    red[r][c4 + 2] = acc.z; red[r][c4 + 3] = acc.w;
    __syncthreads();
    const int col = tid;  // 0..127
    float a = bias[bn * HG + col] + red[0][col] + red[1][col] + red[2][col] + red[3][col];
    float g = 1.0f / (1.0f + expf(-a));
    if (col < HID) {
        z_out[bn * HID + col] = g;                 // z
    } else {
        int hh = col - HID;                        // r gate
        int b  = bn / NN;
        int n  = bn % NN;
        x_T[(size_t)(b * IND + 2 + hh) * NNP + n] = g * h[bn * HID + hh];
    }
}

// K4: n = tanh(sup2 . Wu + bu); out = z*n + (1-z)*h
__global__ void update_kernel(const float* __restrict__ sup,
                              const float* __restrict__ W,
                              const float* __restrict__ bias,
                              const float* __restrict__ z,
                              const float* __restrict__ h,
                              float* __restrict__ out) {
    __shared__ float s[KI];
    __shared__ float red[8][HID];
    const int bn  = blockIdx.x;
    const int tid = threadIdx.x;
    for (int t = tid; t < KI; t += 128) s[t] = sup[bn * KI + t];
    __syncthreads();
    const int r  = tid >> 4;
    const int c4 = (tid & 15) * 4;
    const float* Wp = W + (size_t)bn * KI * HID + c4;
    float4 acc = make_float4(0.f, 0.f, 0.f, 0.f);
    #pragma unroll 8
    for (int i = r; i < KI; i += 8) {
        float4 w = *(const float4*)(Wp + (size_t)i * HID);
        float sv = s[i];
        acc.x += sv * w.x; acc.y += sv * w.y;
        acc.z += sv * w.z; acc.w += sv * w.w;
    }
    red[r][c4 + 0] = acc.x; red[r][c4 + 1] = acc.y;
    red[r][c4 + 2] = acc.z; red[r][c4 + 3] = acc.w;
    __syncthreads();
    if (tid < HID) {
        const int col = tid;
        float a = bias[bn * HID + col];
        #pragma unroll
        for (int rr = 0; rr < 8; ++rr) a += red[rr][col];
        float nn = tanhf(a);
        float zz = z[bn * HID + col];
        float hv = h[bn * HID + col];
        out[bn * HID + col] = zz * nn + (1.f - zz) * hv;
    }
}

extern "C" void kernel_launch(void* const* d_in, const int* in_sizes, int n_in,
                              void* d_out, int out_size, void* d_ws, size_t ws_size,
                              hipStream_t stream) {
    const float* G  = (const float*)d_in[0];
    const float* xt = (const float*)d_in[1];
    const float* h  = (const float*)d_in[2];
    const float* Wg = (const float*)d_in[3];
    const float* bg = (const float*)d_in[4];
    const float* Wu = (const float*)d_in[5];
    const float* bu = (const float*)d_in[6];
    float* out = (float*)d_out;

    float* ws    = (float*)d_ws;
    float* G_p   = ws + OFF_GP;
    float* x_T   = ws + OFF_XT;
    float* sup   = ws + OFF_SUP;
    float* z     = ws + OFF_Z;

    const int totPrep = KCH * NN * NNP + NB * IND * NNP;
    prep_kernel<<<(totPrep + 255) / 256, 256, 0, stream>>>(G, xt, h, G_p, x_T);

    const int totS = NB * NN * IND;
    gcn_kernel<<<(totS + 255) / 256, 256, 0, stream>>>(G_p, x_T, sup);

    gate_kernel<<<NB * NN, 128, 0, stream>>>(sup, Wg, bg, h, z, x_T);

    gcn_kernel<<<(totS + 255) / 256, 256, 0, stream>>>(G_p, x_T, sup);

    update_kernel<<<NB * NN, 128, 0, stream>>>(sup, Wu, bu, z, h, out);
}

// Round 4
// 204.986 us; speedup vs baseline: 1.9454x; 1.3465x over previous
//
#include <hip/hip_runtime.h>
#include <math.h>

#define NB  16
#define NN  307
#define MP  320     // padded m (reduction) dim
#define KCH 3
#define IND 66      // INPUT_DIM + HIDDEN
#define IP  80      // padded i dim
#define KI  198     // KCH * IND
#define HID 64
#define HG  128     // 2 * HIDDEN
#define NT  16      // n-tile per block in gcn
#define MC  32      // m-chunk
#define GLD (MC + 4) // g_l row stride (bank-conflict break)

typedef float f32x4 __attribute__((ext_vector_type(4)));

// ws layout (floats)
#define OFF_GP   0
#define SZ_GP    (KCH * MP * MP)           // 307,200
#define OFF_X    (OFF_GP + SZ_GP)
#define SZ_X     (NB * MP * IP)            // 409,600
#define OFF_SUP  (OFF_X + SZ_X)
#define SZ_SUP   (NB * NN * KI)            // 972,432
#define OFF_Z    (OFF_SUP + SZ_SUP)

// K0: padded G copy [k][n(320)][m(320)] + combined input x[b][m(320)][i(80)]
__global__ void prep_kernel(const float* __restrict__ G,
                            const float* __restrict__ xt,
                            const float* __restrict__ h,
                            float* __restrict__ G_p,
                            float* __restrict__ x) {
    int idx = blockIdx.x * blockDim.x + threadIdx.x;
    const int totG = KCH * MP * MP;
    const int totX = NB * MP * IP;
    if (idx < totG) {
        int mp = idx % MP;
        int nn = (idx / MP) % MP;
        int k  = idx / (MP * MP);
        G_p[idx] = (mp < NN && nn < NN) ? G[(k * NN + nn) * NN + mp] : 0.f;
    } else if (idx < totG + totX) {
        int j  = idx - totG;
        int ip = j % IP;
        int m  = (j / IP) % MP;
        int b  = j / (IP * MP);
        float v = 0.f;
        if (m < NN && ip < IND)
            v = (ip < 2) ? xt[(b * NN + m) * 2 + ip]
                         : h[(b * NN + m) * HID + (ip - 2)];
        x[j] = v;
    }
}

// LDS-tiled batched GEMM: sup[b,n,k*66+i] = sum_m G[k,n,m] * x[b,m,i]
// block = (b, 16-n tile); thread = (n_l, il) owning i = il*4+j (j<4) and i = 64+il.
__global__ __launch_bounds__(256) void gcn_tiled(const float* __restrict__ G_p,
                                                 const float* __restrict__ x,
                                                 float* __restrict__ sup) {
    __shared__ float x_l[MC][IP];         // 10,240 B
    __shared__ float g_l[KCH][NT][GLD];   // 6,912 B
    const int b   = blockIdx.x / 20;      // 20 n-tiles of 16 cover 307 (padded to 320)
    const int n0  = (blockIdx.x % 20) * NT;
    const int tid = threadIdx.x;
    const int n_l = tid >> 4;
    const int il  = tid & 15;
    float acc[KCH][5] = {};
    for (int c = 0; c < MP / MC; ++c) {
        __syncthreads();
        // stage x chunk (2560 floats = 640 float4, fully contiguous)
        const float4* xs = (const float4*)(x + ((size_t)b * MP + c * MC) * IP);
        float4* xl4 = (float4*)&x_l[0][0];
        for (int t = tid; t < MC * IP / 4; t += 256) xl4[t] = xs[t];
        // stage G chunk (3*16 rows x 32 floats = 384 float4)
        for (int t = tid; t < KCH * NT * MC / 4; t += 256) {
            int m4 = t & 7;
            int nr = (t >> 3) & 15;
            int k  = t >> 7;
            float4 g = *(const float4*)(G_p + ((size_t)k * MP + n0 + nr) * MP + c * MC + m4 * 4);
            *(float4*)&g_l[k][nr][m4 * 4] = g;
        }
        __syncthreads();
        #pragma unroll 4
        for (int m = 0; m < MC; ++m) {
            float4 xq = *(const float4*)&x_l[m][il * 4];
            float xe  = x_l[m][64 + il];
            #pragma unroll
            for (int k = 0; k < KCH; ++k) {
                float gv = g_l[k][n_l][m];
                acc[k][0] += gv * xq.x;
                acc[k][1] += gv * xq.y;
                acc[k][2] += gv * xq.z;
                acc[k][3] += gv * xq.w;
                acc[k][4] += gv * xe;
            }
        }
    }
    const int n = n0 + n_l;
    if (n < NN) {
        float* sp = sup + (size_t)(b * NN + n) * KI;
        #pragma unroll
        for (int k = 0; k < KCH; ++k) {
            #pragma unroll
            for (int j = 0; j < 4; ++j)
                sp[k * IND + il * 4 + j] = acc[k][j];
            if (il < 2) sp[k * IND + 64 + il] = acc[k][4];
        }
    }
}

// K2: gates = sigmoid(sup . W + b); z stored; cand r*h written into x rows 2..65
__global__ void gate_kernel(const float* __restrict__ sup,
                            const float* __restrict__ W,
                            const float* __restrict__ bias,
                            const float* __restrict__ h,
                            float* __restrict__ z_out,
                            float* __restrict__ x) {
    __shared__ float s[KI];
    __shared__ float red[4][HG];
    const int bn  = blockIdx.x;
    const int tid = threadIdx.x;
    for (int t = tid; t < KI; t += 128) s[t] = sup[bn * KI + t];
    __syncthreads();
    const int r  = tid >> 5;
    const int c4 = (tid & 31) * 4;
    const f32x4* Wp = (const f32x4*)(W + (size_t)bn * KI * HG + c4);
    float4 acc = make_float4(0.f, 0.f, 0.f, 0.f);
    #pragma unroll 8
    for (int i = r; i < KI; i += 4) {
        f32x4 w = __builtin_nontemporal_load(Wp + (size_t)i * (HG / 4));
        float sv = s[i];
        acc.x += sv * w.x; acc.y += sv * w.y;
        acc.z += sv * w.z; acc.w += sv * w.w;
    }
    red[r][c4 + 0] = acc.x; red[r][c4 + 1] = acc.y;
    red[r][c4 + 2] = acc.z; red[r][c4 + 3] = acc.w;
    __syncthreads();
    const int col = tid;  // 0..127
    float a = bias[bn * HG + col] + red[0][col] + red[1][col] + red[2][col] + red[3][col];
    float g = 1.0f / (1.0f + expf(-a));
    if (col < HID) {
        z_out[bn * HID + col] = g;                 // z
    } else {
        int hh = col - HID;                        // r gate
        int b  = bn / NN;
        int n  = bn % NN;
        x[((size_t)b * MP + n) * IP + 2 + hh] = g * h[bn * HID + hh];
    }
}

// K4: n = tanh(sup2 . Wu + bu); out = z*n + (1-z)*h
__global__ void update_kernel(const float* __restrict__ sup,
                              const float* __restrict__ W,
                              const float* __restrict__ bias,
                              const float* __restrict__ z,
                              const float* __restrict__ h,
                              float* __restrict__ out) {
    __shared__ float s[KI];
    __shared__ float red[8][HID];
    const int bn  = blockIdx.x;
    const int tid = threadIdx.x;
    for (int t = tid; t < KI; t += 128) s[t] = sup[bn * KI + t];
    __syncthreads();
    const int r  = tid >> 4;
    const int c4 = (tid & 15) * 4;
    const f32x4* Wp = (const f32x4*)(W + (size_t)bn * KI * HID + c4);
    float4 acc = make_float4(0.f, 0.f, 0.f, 0.f);
    #pragma unroll 8
    for (int i = r; i < KI; i += 8) {
        f32x4 w = __builtin_nontemporal_load(Wp + (size_t)i * (HID / 4));
        float sv = s[i];
        acc.x += sv * w.x; acc.y += sv * w.y;
        acc.z += sv * w.z; acc.w += sv * w.w;
    }
    red[r][c4 + 0] = acc.x; red[r][c4 + 1] = acc.y;
    red[r][c4 + 2] = acc.z; red[r][c4 + 3] = acc.w;
    __syncthreads();
    if (tid < HID) {
        const int col = tid;
        float a = bias[bn * HID + col];
        #pragma unroll
        for (int rr = 0; rr < 8; ++rr) a += red[rr][col];
        float nn = tanhf(a);
        float zz = z[bn * HID + col];
        float hv = h[bn * HID + col];
        out[bn * HID + col] = zz * nn + (1.f - zz) * hv;
    }
}

extern "C" void kernel_launch(void* const* d_in, const int* in_sizes, int n_in,
                              void* d_out, int out_size, void* d_ws, size_t ws_size,
                              hipStream_t stream) {
    const float* G  = (const float*)d_in[0];
    const float* xt = (const float*)d_in[1];
    const float* h  = (const float*)d_in[2];
    const float* Wg = (const float*)d_in[3];
    const float* bg = (const float*)d_in[4];
    const float* Wu = (const float*)d_in[5];
    const float* bu = (const float*)d_in[6];
    float* out = (float*)d_out;

    float* ws   = (float*)d_ws;
    float* G_p  = ws + OFF_GP;
    float* x    = ws + OFF_X;
    float* sup  = ws + OFF_SUP;
    float* z    = ws + OFF_Z;

    const int totPrep = KCH * MP * MP + NB * MP * IP;
    prep_kernel<<<(totPrep + 255) / 256, 256, 0, stream>>>(G, xt, h, G_p, x);

    gcn_tiled<<<NB * 20, 256, 0, stream>>>(G_p, x, sup);

    gate_kernel<<<NB * NN, 128, 0, stream>>>(sup, Wg, bg, h, z, x);

    gcn_tiled<<<NB * 20, 256, 0, stream>>>(G_p, x, sup);

    update_kernel<<<NB * NN, 128, 0, stream>>>(sup, Wu, bu, z, h, out);
}